// Round 8
// baseline (343.379 us; speedup 1.0000x reference)
//
#include <hip/hip_runtime.h>
#include <math.h>

// GCN 3-layer, bf16 features + MFMA, gather fused with the following GEMM.
//   K1: y1 = bf16(dinv * (x @ W1))                      (persistent MFMA kernel)
//   K2: y2 = bf16(dinv * (relu(dinv*(A y1) + b1) @ W2)) (fused gather+MFMA)
//   K3: y3 = bf16(dinv * (relu(dinv*(A y2) + b2) @ W3)) (fused gather+MFMA, 64ch out)
//   K4: out = log_softmax(dinv*(A y3) + b3)             (gather + wave softmax)
// CSR built once per call via 2-phase LDS bucket sort (bucket = dst>>8).
// deg = indeg(dst) + 1 (self loop).

#define NN 100000
#define NE 1600000
#define NBUK 391          // ceil(100000/256)
#define BCAP 4608         // slots per bucket (mean 4096, sd 64 -> 8 sd headroom)

typedef float floatx4 __attribute__((ext_vector_type(4)));
typedef short short8 __attribute__((ext_vector_type(8)));

__device__ __forceinline__ unsigned short f2bf(float f) {
    unsigned u = __float_as_uint(f);
    unsigned r = (u + 0x7fffu + ((u >> 16) & 1u)) >> 16;   // RNE
    return (unsigned short)r;
}
__device__ __forceinline__ float bflo(unsigned u) { return __uint_as_float(u << 16); }
__device__ __forceinline__ float bfhi(unsigned u) { return __uint_as_float(u & 0xffff0000u); }

// ---------------- W prep: fp32 [K][NC] -> bf16 [NC][K] (transposed) ----------------
__global__ __launch_bounds__(256) void k_wprep(const float* __restrict__ W, unsigned short* __restrict__ Wtg,
                                               int K, int NC) {
    int idx = blockIdx.x * 256 + threadIdx.x;
    if (idx >= NC * K) return;
    int n = idx / K, k = idx - n * K;
    Wtg[idx] = f2bf(W[k * NC + n]);
}

// ---------------- CSR build: phase A — bucketize ----------------
__global__ __launch_bounds__(256) void k_bucket(const int4* __restrict__ src4, const int4* __restrict__ dst4,
                                                int* __restrict__ bcur, int* __restrict__ bbuf, int E) {
    __shared__ int hist[NBUK];
    __shared__ int base[NBUK];
    int t = threadIdx.x;
    for (int b = t; b < NBUK; b += 256) hist[b] = 0;
    __syncthreads();
    int E4 = E >> 2;
    int q0 = blockIdx.x * 1024;
    #pragma unroll
    for (int j = 0; j < 4; j++) {
        int q = q0 + j * 256 + t;
        if (q < E4) {
            int4 d = dst4[q];
            atomicAdd(&hist[d.x >> 8], 1);
            atomicAdd(&hist[d.y >> 8], 1);
            atomicAdd(&hist[d.z >> 8], 1);
            atomicAdd(&hist[d.w >> 8], 1);
        }
    }
    __syncthreads();
    for (int b = t; b < NBUK; b += 256) {
        int c = hist[b];
        base[b] = c ? atomicAdd(&bcur[b], c) : 0;
        hist[b] = 0;
    }
    __syncthreads();
    #pragma unroll
    for (int j = 0; j < 4; j++) {
        int q = q0 + j * 256 + t;
        if (q < E4) {
            int4 s = src4[q];
            int4 d = dst4[q];
            int sv[4] = {s.x, s.y, s.z, s.w};
            int dv[4] = {d.x, d.y, d.z, d.w};
            #pragma unroll
            for (int u = 0; u < 4; u++) {
                int b = dv[u] >> 8;
                int r = atomicAdd(&hist[b], 1);
                int pos = base[b] + r;
                if (pos < BCAP) bbuf[b * BCAP + pos] = (sv[u] << 8) | (dv[u] & 255);
            }
        }
    }
}

// exclusive scan of bucket counts (single wave), also row_ptr[N] = E
__global__ void k_scanbuckets(const int* __restrict__ bcur, int* __restrict__ bbase, int nb,
                              int* __restrict__ row_ptr, int n, int E) {
    int lane = threadIdx.x;
    int carry = 0;
    for (int base = 0; base < nb; base += 64) {
        int idx = base + lane;
        int v = (idx < nb) ? min(bcur[idx], BCAP) : 0;
        int orig = v;
        #pragma unroll
        for (int o = 1; o < 64; o <<= 1) {
            int u = __shfl_up(v, o);
            if (lane >= o) v += u;
        }
        if (idx < nb) bbase[idx] = carry + v - orig;
        carry += __shfl(v, 63);
    }
    if (lane == 0) row_ptr[n] = E;
}

// ---------------- CSR build: phase B — per-bucket counting sort in LDS ----------------
__global__ __launch_bounds__(256) void k_build(const int* __restrict__ bcur, const int* __restrict__ bbase,
                                               const int* __restrict__ bbuf,
                                               int* __restrict__ row_ptr, int* __restrict__ csr, int N) {
    __shared__ int sh[256];
    __shared__ int cur[256];
    __shared__ int loc[BCAP];
    int b = blockIdx.x, t = threadIdx.x;
    int cnt = min(bcur[b], BCAP);
    int gbase = bbase[b];
    const int* bp = bbuf + b * BCAP;
    sh[t] = 0;
    __syncthreads();
    for (int i = t; i < cnt; i += 256) atomicAdd(&sh[bp[i] & 255], 1);
    __syncthreads();
    int v = sh[t];
    for (int o = 1; o < 256; o <<= 1) {
        int u = (t >= o) ? sh[t - o] : 0;
        __syncthreads();
        sh[t] += u;
        __syncthreads();
    }
    int excl = sh[t] - v;
    int node = b * 256 + t;
    if (node < N) row_ptr[node] = gbase + excl;
    cur[t] = excl;
    __syncthreads();
    for (int i = t; i < cnt; i += 256) {
        int p = bp[i];
        int r = atomicAdd(&cur[p & 255], 1);
        loc[r] = p >> 8;                       // src
    }
    __syncthreads();
    for (int i = t; i < cnt; i += 256) csr[gbase + i] = loc[i];
}

__global__ __launch_bounds__(256) void k_dinv(const int* __restrict__ row_ptr, float* __restrict__ dinv, int n) {
    int i = blockIdx.x * 256 + threadIdx.x;
    if (i < n) {
        int d = row_ptr[i + 1] - row_ptr[i];
        dinv[i] = rsqrtf((float)d + 1.0f);
    }
}

// ---------------- K1: MFMA GEMM (fp32 A in-register cvt): Y = bf16(dinv*(A @ W)) ----------------
// Persistent: 512 blocks, register double-buffer prefetch; LDS-staged coalesced epilogue.
// Layouts (16x16x32 bf16): A: lane holds A[m=lane&15][k=quad*8+j]; B: lane holds B[k=quad*8+j][n=lane&15];
// C/D: col=lane&15, row=quad*4+reg.

__global__ __launch_bounds__(256) void k_mfma1(const float* __restrict__ Av, const unsigned short* __restrict__ Wtg,
                                               const float* __restrict__ dinv, unsigned short* __restrict__ Y, int M) {
    constexpr int K = 128, NC = 128, NT = 8, NU = 4;
    __shared__ unsigned short Wt[NC][136];
    __shared__ unsigned short Ost[4][16][NC + 8];
    int t = threadIdx.x;
    for (int idx = t; idx < NC * 16; idx += 256) {
        int nrow = idx >> 4, chunk = idx & 15;
        *(uint4*)&Wt[nrow][chunk * 8] = *(const uint4*)(Wtg + nrow * K + chunk * 8);
    }
    __syncthreads();
    int lane = t & 63, wid = t >> 6;
    int col = lane & 15, quad = lane >> 4;
    int nstrips = M / 16;
    int stride = gridDim.x * 4;
    int s = blockIdx.x * 4 + wid;
    if (s >= nstrips) return;

    auto loadA = [&](int strip, short8 af[4]) {
        const float* Af = Av + (size_t)(strip * 16 + col) * K + quad * 8;
        #pragma unroll
        for (int ks = 0; ks < 4; ks++) {
            float4 f0 = *(const float4*)(Af + ks * 32);
            float4 f1 = *(const float4*)(Af + ks * 32 + 4);
            short8 v;
            v[0] = (short)f2bf(f0.x); v[1] = (short)f2bf(f0.y); v[2] = (short)f2bf(f0.z); v[3] = (short)f2bf(f0.w);
            v[4] = (short)f2bf(f1.x); v[5] = (short)f2bf(f1.y); v[6] = (short)f2bf(f1.z); v[7] = (short)f2bf(f1.w);
            af[ks] = v;
        }
    };

    short8 cur[4];
    loadA(s, cur);
    while (true) {
        int snext = s + stride;
        bool has = (snext < nstrips);
        short8 nxt[4];
        if (has) loadA(snext, nxt);

        floatx4 acc[NT];
        #pragma unroll
        for (int i = 0; i < NT; i++) acc[i] = (floatx4){0.f, 0.f, 0.f, 0.f};
        #pragma unroll
        for (int ks = 0; ks < 4; ks++) {
            #pragma unroll
            for (int nt = 0; nt < NT; nt++) {
                short8 bfrag = *(const short8*)&Wt[nt * 16 + col][ks * 32 + quad * 8];
                acc[nt] = __builtin_amdgcn_mfma_f32_16x16x32_bf16(cur[ks], bfrag, acc[nt], 0, 0, 0);
            }
        }
        int row0 = s * 16;
        #pragma unroll
        for (int r = 0; r < 4; r++) {
            float dv = dinv[row0 + quad * 4 + r];
            #pragma unroll
            for (int nt = 0; nt < NT; nt++)
                Ost[wid][quad * 4 + r][nt * 16 + col] = f2bf(acc[nt][r] * dv);
        }
        #pragma unroll
        for (int i = 0; i < NU; i++) {
            int idx = i * 64 + lane;
            int rr = idx >> 4, cc = idx & 15;
            ((uint4*)&Y[(size_t)(row0 + rr) * NC])[cc] = *(uint4*)&Ost[wid][rr][cc * 8];
        }
        if (!has) break;
        s = snext;
        #pragma unroll
        for (int ks = 0; ks < 4; ks++) cur[ks] = nxt[ks];
    }
}

// ---------------- fused gather + relu + MFMA: Yout = bf16(dinv*(relu(dinv*(A y)+b) @ W)) ----------------
// Block = 256 threads = one 16-node strip per iteration (persistent over strips).
// Gather: 16 threads/node, 8ch (uint4) each, 8-deep pipelined row loads.
// MFMA: h-tile in LDS is the A operand; W pre-staged in LDS; wave w owns output cols [w*CW, (w+1)*CW).

__device__ __forceinline__ void acc8(float* a, uint4 v) {
    a[0] += bflo(v.x); a[1] += bfhi(v.x);
    a[2] += bflo(v.y); a[3] += bfhi(v.y);
    a[4] += bflo(v.z); a[5] += bfhi(v.z);
    a[6] += bflo(v.w); a[7] += bfhi(v.w);
}

template <int NCOUT>
__global__ __launch_bounds__(256) void k_gather_mfma(const uint4* __restrict__ y, const int* __restrict__ csr,
                                                     const int* __restrict__ row_ptr, const float* __restrict__ dinv,
                                                     const float* __restrict__ bias,
                                                     const unsigned short* __restrict__ Wtg,
                                                     unsigned short* __restrict__ Yout, int M) {
    constexpr int K = 128;
    constexpr int CW = NCOUT / 4;       // output cols per wave
    constexpr int NTW = CW / 16;        // n-tiles per wave
    __shared__ unsigned short Wt[NCOUT][136];
    __shared__ unsigned short Hs[16][136];
    __shared__ unsigned short Ys[4][16][CW + 8];

    int t = threadIdx.x;
    for (int idx = t; idx < NCOUT * 16; idx += 256) {
        int nrow = idx >> 4, chunk = idx & 15;
        *(uint4*)&Wt[nrow][chunk * 8] = *(const uint4*)(Wtg + nrow * K + chunk * 8);
    }
    __syncthreads();

    int lane = t & 63, wid = t >> 6;
    int col = lane & 15, quad = lane >> 4;
    int m = t >> 4;                 // gather: node within strip
    int c = t & 15;                 // gather: uint4 channel group
    float4 b0 = ((const float4*)bias)[c * 2];
    float4 b1 = ((const float4*)bias)[c * 2 + 1];

    int nstrips = M / 16;
    for (int s = blockIdx.x; s < nstrips; s += gridDim.x) {
        int node = s * 16 + m;
        int s0 = row_ptr[node], s1 = row_ptr[node + 1];
        float a[8] = {};
        acc8(a, y[(size_t)node * 16 + c]);       // self loop
        int p = s0;
        int i0, i1, i2, i3, i4, i5, i6, i7;
        if (p + 8 <= s1) {
            i0 = csr[p]; i1 = csr[p+1]; i2 = csr[p+2]; i3 = csr[p+3];
            i4 = csr[p+4]; i5 = csr[p+5]; i6 = csr[p+6]; i7 = csr[p+7];
            while (true) {
                uint4 v0 = y[(size_t)i0 * 16 + c], v1 = y[(size_t)i1 * 16 + c];
                uint4 v2 = y[(size_t)i2 * 16 + c], v3 = y[(size_t)i3 * 16 + c];
                uint4 v4 = y[(size_t)i4 * 16 + c], v5 = y[(size_t)i5 * 16 + c];
                uint4 v6 = y[(size_t)i6 * 16 + c], v7 = y[(size_t)i7 * 16 + c];
                p += 8;
                bool nxt = (p + 8 <= s1);
                if (nxt) {
                    i0 = csr[p]; i1 = csr[p+1]; i2 = csr[p+2]; i3 = csr[p+3];
                    i4 = csr[p+4]; i5 = csr[p+5]; i6 = csr[p+6]; i7 = csr[p+7];
                }
                acc8(a, v0); acc8(a, v1); acc8(a, v2); acc8(a, v3);
                acc8(a, v4); acc8(a, v5); acc8(a, v6); acc8(a, v7);
                if (!nxt) break;
            }
        }
        if (p + 4 <= s1) {
            int j0 = csr[p], j1 = csr[p+1], j2 = csr[p+2], j3 = csr[p+3];
            uint4 v0 = y[(size_t)j0 * 16 + c], v1 = y[(size_t)j1 * 16 + c];
            uint4 v2 = y[(size_t)j2 * 16 + c], v3 = y[(size_t)j3 * 16 + c];
            acc8(a, v0); acc8(a, v1); acc8(a, v2); acc8(a, v3);
            p += 4;
        }
        for (; p < s1; p++) acc8(a, y[(size_t)csr[p] * 16 + c]);
        float sc = dinv[node];
        float r0 = fmaxf(sc * a[0] + b0.x, 0.f), r1 = fmaxf(sc * a[1] + b0.y, 0.f);
        float r2 = fmaxf(sc * a[2] + b0.z, 0.f), r3 = fmaxf(sc * a[3] + b0.w, 0.f);
        float r4 = fmaxf(sc * a[4] + b1.x, 0.f), r5 = fmaxf(sc * a[5] + b1.y, 0.f);
        float r6 = fmaxf(sc * a[6] + b1.z, 0.f), r7 = fmaxf(sc * a[7] + b1.w, 0.f);
        uint4 o;
        o.x = ((unsigned)f2bf(r1) << 16) | f2bf(r0);
        o.y = ((unsigned)f2bf(r3) << 16) | f2bf(r2);
        o.z = ((unsigned)f2bf(r5) << 16) | f2bf(r4);
        o.w = ((unsigned)f2bf(r7) << 16) | f2bf(r6);
        *(uint4*)&Hs[m][c * 8] = o;
        __syncthreads();

        // MFMA: h-tile @ W  (A from Hs, B from Wt)
        floatx4 acc[NTW];
        #pragma unroll
        for (int j = 0; j < NTW; j++) acc[j] = (floatx4){0.f, 0.f, 0.f, 0.f};
        #pragma unroll
        for (int ks = 0; ks < 4; ks++) {
            short8 af = *(const short8*)&Hs[col][ks * 32 + quad * 8];
            #pragma unroll
            for (int j = 0; j < NTW; j++) {
                short8 bf = *(const short8*)&Wt[wid * CW + j * 16 + col][ks * 32 + quad * 8];
                acc[j] = __builtin_amdgcn_mfma_f32_16x16x32_bf16(af, bf, acc[j], 0, 0, 0);
            }
        }
        #pragma unroll
        for (int r = 0; r < 4; r++) {
            int rr = quad * 4 + r;
            float dv = dinv[s * 16 + rr];
            #pragma unroll
            for (int j = 0; j < NTW; j++)
                Ys[wid][rr][j * 16 + col] = f2bf(acc[j][r] * dv);
        }
        // same-wave readback, coalesced stores (wave owns cols [wid*CW, wid*CW+CW))
        if (NCOUT == 128) {
            int rr = lane >> 2, cc = lane & 3;
            uint4 v = *(uint4*)&Ys[wid][rr][cc * 8];
            *(uint4*)&Yout[(size_t)(s * 16 + rr) * NCOUT + wid * CW + cc * 8] = v;
        } else {
            if (lane < 32) {
                int rr = lane >> 1, cc = lane & 1;
                uint4 v = *(uint4*)&Ys[wid][rr][cc * 8];
                *(uint4*)&Yout[(size_t)(s * 16 + rr) * NCOUT + wid * CW + cc * 8] = v;
            }
        }
        __syncthreads();   // protect Hs before next strip's gather writes
    }
}

// ---------------- K4: 64ch gather + log-softmax: 8 threads/node, 8 ch per thread ----------------
__global__ __launch_bounds__(256) void k_gather_lsm_bf(const uint4* __restrict__ y, const int* __restrict__ csr,
                                                       const int* __restrict__ row_ptr, const float* __restrict__ dinv,
                                                       const float* __restrict__ bias, float4* __restrict__ out4, int n) {
    int node = blockIdx.x * 32 + (threadIdx.x >> 3);
    int c = threadIdx.x & 7;
    if (node >= n) return;
    int s0 = row_ptr[node], s1 = row_ptr[node + 1];
    float a[8] = {};
    acc8(a, y[(size_t)node * 8 + c]);
    int p = s0;
    for (; p + 4 <= s1; p += 4) {
        int i0 = csr[p], i1 = csr[p + 1], i2 = csr[p + 2], i3 = csr[p + 3];
        uint4 v0 = y[(size_t)i0 * 8 + c];
        uint4 v1 = y[(size_t)i1 * 8 + c];
        uint4 v2 = y[(size_t)i2 * 8 + c];
        uint4 v3 = y[(size_t)i3 * 8 + c];
        acc8(a, v0); acc8(a, v1); acc8(a, v2); acc8(a, v3);
    }
    for (; p < s1; p++) acc8(a, y[(size_t)csr[p] * 8 + c]);
    float s = dinv[node];
    float4 b0 = ((const float4*)bias)[c * 2];
    float4 b1 = ((const float4*)bias)[c * 2 + 1];
    float v[8];
    v[0] = s * a[0] + b0.x; v[1] = s * a[1] + b0.y; v[2] = s * a[2] + b0.z; v[3] = s * a[3] + b0.w;
    v[4] = s * a[4] + b1.x; v[5] = s * a[5] + b1.y; v[6] = s * a[6] + b1.z; v[7] = s * a[7] + b1.w;
    float m = v[0];
    #pragma unroll
    for (int i = 1; i < 8; i++) m = fmaxf(m, v[i]);
    #pragma unroll
    for (int o = 4; o > 0; o >>= 1) m = fmaxf(m, __shfl_xor(m, o));
    float sum = 0.f;
    #pragma unroll
    for (int i = 0; i < 8; i++) sum += expf(v[i] - m);
    #pragma unroll
    for (int o = 4; o > 0; o >>= 1) sum += __shfl_xor(sum, o);
    float lse = m + logf(sum);
    out4[(size_t)node * 16 + c * 2]     = make_float4(v[0] - lse, v[1] - lse, v[2] - lse, v[3] - lse);
    out4[(size_t)node * 16 + c * 2 + 1] = make_float4(v[4] - lse, v[5] - lse, v[6] - lse, v[7] - lse);
}

// ---------------- launch ----------------

extern "C" void kernel_launch(void* const* d_in, const int* in_sizes, int n_in,
                              void* d_out, int out_size, void* d_ws, size_t ws_size,
                              hipStream_t stream) {
    const float* x  = (const float*)d_in[0];
    const int*   ei = (const int*)d_in[1];
    const float* W1 = (const float*)d_in[2];
    const float* b1 = (const float*)d_in[3];
    const float* W2 = (const float*)d_in[4];
    const float* b2 = (const float*)d_in[5];
    const float* W3 = (const float*)d_in[6];
    const float* b3 = (const float*)d_in[7];
    float* out = (float*)d_out;

    const int N = NN, E = NE;
    const int nb = (N + 255) / 256;

    char* ws = (char*)d_ws;
    size_t off = 0;
    auto alloc = [&](size_t bytes) -> void* {
        void* p = ws + off;
        off += bytes;
        off = (off + 255) & ~(size_t)255;
        return p;
    };
    int*            row_ptr = (int*)alloc((size_t)(N + 1) * 4);
    float*          dinvv   = (float*)alloc((size_t)N * 4);
    int*            bcur    = (int*)alloc(512 * 4);
    int*            bbase   = (int*)alloc(512 * 4);
    int*            bbuf    = (int*)alloc((size_t)NBUK * BCAP * 4);
    int*            csr     = (int*)alloc((size_t)E * 4);
    unsigned short* wt1     = (unsigned short*)alloc(128 * 128 * 2);
    unsigned short* wt2     = (unsigned short*)alloc(128 * 128 * 2);
    unsigned short* wt3     = (unsigned short*)alloc(64 * 128 * 2);
    unsigned short* yb      = (unsigned short*)alloc((size_t)N * 128 * 2);
    unsigned short* y2      = (unsigned short*)alloc((size_t)N * 128 * 2);
    unsigned short* y3      = (unsigned short*)alloc((size_t)N * 64 * 2);
    (void)ws_size; (void)in_sizes; (void)n_in; (void)out_size;

    const int* srcp = ei;
    const int* dstp = ei + E;

    hipMemsetAsync(bcur, 0, 512 * 4, stream);
    k_wprep<<<64, 256, 0, stream>>>(W1, wt1, 128, 128);
    k_wprep<<<64, 256, 0, stream>>>(W2, wt2, 128, 128);
    k_wprep<<<32, 256, 0, stream>>>(W3, wt3, 128, 64);
    k_bucket<<<(E + 4095) / 4096, 256, 0, stream>>>((const int4*)srcp, (const int4*)dstp, bcur, bbuf, E);
    k_scanbuckets<<<1, 64, 0, stream>>>(bcur, bbase, NBUK, row_ptr, N, E);
    k_build<<<NBUK, 256, 0, stream>>>(bcur, bbase, bbuf, row_ptr, csr, N);
    k_dinv<<<nb, 256, 0, stream>>>(row_ptr, dinvv, N);

    // K1: y1 = bf16(dinv * (x @ W1))
    k_mfma1<<<512, 256, 0, stream>>>(x, wt1, dinvv, yb, N);
    // K2: fused gather(y1)+relu(b1)+GEMM(W2) -> y2
    k_gather_mfma<128><<<1024, 256, 0, stream>>>((const uint4*)yb, csr, row_ptr, dinvv, b1, wt2, y2, N);
    // K3: fused gather(y2)+relu(b2)+GEMM(W3) -> y3 (64ch)
    k_gather_mfma<64><<<1024, 256, 0, stream>>>((const uint4*)y2, csr, row_ptr, dinvv, b2, wt3, y3, N);
    // K4: gather(y3)+bias(b3)+log-softmax -> out
    k_gather_lsm_bf<<<N / 32, 256, 0, stream>>>((const uint4*)y3, csr, row_ptr, dinvv, b3, (float4*)out, N);
}

// Round 9
// 331.529 us; speedup vs baseline: 1.0357x; 1.0357x over previous
//
#include <hip/hip_runtime.h>
#include <math.h>

// GCN 3-layer, bf16 features + MFMA GEMM (unfused: R8 fusion experiment regressed).
//   per layer: y = bf16(dinv * (H @ W)); h = relu(dinv*(A y + y) + b); final log-softmax.
// CSR built once per call via 2-phase LDS bucket sort (bucket = dst>>8).
// deg = indeg(dst) + 1 (self loop). Gathers run at the ~3.6 TB/s random-row LLC ceiling
// with FETCH ~189 MB = 8 XCDs x ~22 MB distinct-row compulsory traffic (structural).

#define NN 100000
#define NE 1600000
#define NBUK 391          // ceil(100000/256)
#define BCAP 4608         // slots per bucket (mean 4096, sd 64 -> 8 sd headroom)

typedef float floatx4 __attribute__((ext_vector_type(4)));
typedef short short8 __attribute__((ext_vector_type(8)));

__device__ __forceinline__ unsigned short f2bf(float f) {
    unsigned u = __float_as_uint(f);
    unsigned r = (u + 0x7fffu + ((u >> 16) & 1u)) >> 16;   // RNE
    return (unsigned short)r;
}
__device__ __forceinline__ float bflo(unsigned u) { return __uint_as_float(u << 16); }
__device__ __forceinline__ float bfhi(unsigned u) { return __uint_as_float(u & 0xffff0000u); }

// ---------------- W prep (all 3): fp32 [K][NC] -> bf16 [NC][K] (transposed) ----------------
__global__ __launch_bounds__(256) void k_wprep_all(const float* __restrict__ W1, const float* __restrict__ W2,
                                                   const float* __restrict__ W3,
                                                   unsigned short* __restrict__ wt1, unsigned short* __restrict__ wt2,
                                                   unsigned short* __restrict__ wt3) {
    int idx = blockIdx.x * 256 + threadIdx.x;
    if (idx < 16384) {
        int n = idx >> 7, k = idx & 127;
        wt1[idx] = f2bf(W1[k * 128 + n]);
    } else if (idx < 32768) {
        int i = idx - 16384;
        int n = i >> 7, k = i & 127;
        wt2[i] = f2bf(W2[k * 128 + n]);
    } else if (idx < 40960) {
        int i = idx - 32768;
        int n = i >> 7, k = i & 127;       // wt3[n][k], n<64
        wt3[i] = f2bf(W3[k * 64 + n]);
    }
}

// ---------------- CSR build: phase A — bucketize (edges cached in registers across passes) ----------------
__global__ __launch_bounds__(256) void k_bucket(const int4* __restrict__ src4, const int4* __restrict__ dst4,
                                                int* __restrict__ bcur, int* __restrict__ bbuf, int E) {
    __shared__ int hist[NBUK];
    __shared__ int base[NBUK];
    int t = threadIdx.x;
    for (int b = t; b < NBUK; b += 256) hist[b] = 0;
    __syncthreads();
    int E4 = E >> 2;
    int q0 = blockIdx.x * 1024;
    int4 sv[4], dv[4];
    bool valid[4];
    #pragma unroll
    for (int j = 0; j < 4; j++) {
        int q = q0 + j * 256 + t;
        valid[j] = (q < E4);
        if (valid[j]) {
            sv[j] = src4[q];
            dv[j] = dst4[q];
            atomicAdd(&hist[dv[j].x >> 8], 1);
            atomicAdd(&hist[dv[j].y >> 8], 1);
            atomicAdd(&hist[dv[j].z >> 8], 1);
            atomicAdd(&hist[dv[j].w >> 8], 1);
        }
    }
    __syncthreads();
    for (int b = t; b < NBUK; b += 256) {
        int c = hist[b];
        base[b] = c ? atomicAdd(&bcur[b], c) : 0;
        hist[b] = 0;
    }
    __syncthreads();
    #pragma unroll
    for (int j = 0; j < 4; j++) {
        if (valid[j]) {
            int ss[4] = {sv[j].x, sv[j].y, sv[j].z, sv[j].w};
            int dd[4] = {dv[j].x, dv[j].y, dv[j].z, dv[j].w};
            #pragma unroll
            for (int u = 0; u < 4; u++) {
                int b = dd[u] >> 8;
                int r = atomicAdd(&hist[b], 1);
                int pos = base[b] + r;
                if (pos < BCAP) bbuf[b * BCAP + pos] = (ss[u] << 8) | (dd[u] & 255);
            }
        }
    }
}

// exclusive scan of bucket counts (single wave), also row_ptr[N] = E
__global__ void k_scanbuckets(const int* __restrict__ bcur, int* __restrict__ bbase, int nb,
                              int* __restrict__ row_ptr, int n, int E) {
    int lane = threadIdx.x;
    int carry = 0;
    for (int base = 0; base < nb; base += 64) {
        int idx = base + lane;
        int v = (idx < nb) ? min(bcur[idx], BCAP) : 0;
        int orig = v;
        #pragma unroll
        for (int o = 1; o < 64; o <<= 1) {
            int u = __shfl_up(v, o);
            if (lane >= o) v += u;
        }
        if (idx < nb) bbase[idx] = carry + v - orig;
        carry += __shfl(v, 63);
    }
    if (lane == 0) row_ptr[n] = E;
}

// ---------------- CSR build: phase B — per-bucket counting sort in LDS (+ fused dinv) ----------------
__global__ __launch_bounds__(256) void k_build(const int* __restrict__ bcur, const int* __restrict__ bbase,
                                               const int* __restrict__ bbuf,
                                               int* __restrict__ row_ptr, int* __restrict__ csr,
                                               float* __restrict__ dinv, int N) {
    __shared__ int sh[256];
    __shared__ int cur[256];
    __shared__ int loc[BCAP];
    int b = blockIdx.x, t = threadIdx.x;
    int cnt = min(bcur[b], BCAP);
    int gbase = bbase[b];
    const int* bp = bbuf + b * BCAP;
    sh[t] = 0;
    __syncthreads();
    for (int i = t; i < cnt; i += 256) atomicAdd(&sh[bp[i] & 255], 1);
    __syncthreads();
    int v = sh[t];
    for (int o = 1; o < 256; o <<= 1) {
        int u = (t >= o) ? sh[t - o] : 0;
        __syncthreads();
        sh[t] += u;
        __syncthreads();
    }
    int excl = sh[t] - v;
    int node = b * 256 + t;
    if (node < N) {
        row_ptr[node] = gbase + excl;
        dinv[node] = rsqrtf((float)v + 1.0f);   // deg = indeg + 1 (self loop)
    }
    cur[t] = excl;
    __syncthreads();
    for (int i = t; i < cnt; i += 256) {
        int p = bp[i];
        int r = atomicAdd(&cur[p & 255], 1);
        loc[r] = p >> 8;                       // src
    }
    __syncthreads();
    for (int i = t; i < cnt; i += 256) csr[gbase + i] = loc[i];
}

// ---------------- MFMA GEMM: Y[M,NC](bf16) = bf16( (A[M,128] @ W[128,NC]) * dinv[row] )
// Persistent: each wave loops strips with register double-buffer prefetch.
// Wtg pre-transposed bf16 [NC][K]; staged into LDS once per block.
// Epilogue staged through per-wave LDS tile -> coalesced uint4 stores.
// Layouts (16x16x32 bf16): A: lane holds A[m=lane&15][k=quad*8+j]; B: lane holds B[k=quad*8+j][n=lane&15];
// C/D: col=lane&15, row=quad*4+reg.

template <int NC, bool CVT>
__global__ __launch_bounds__(256) void k_mfma(const void* __restrict__ Av, const unsigned short* __restrict__ Wtg,
                                              const float* __restrict__ dinv, unsigned short* __restrict__ Y, int M) {
    constexpr int K = 128;
    constexpr int NT = NC / 16;
    constexpr int NU = NC / 32;
    __shared__ unsigned short Wt[NC][136];
    __shared__ unsigned short Ost[4][16][NC + 8];
    int t = threadIdx.x;
    for (int idx = t; idx < NC * 16; idx += 256) {
        int nrow = idx >> 4, chunk = idx & 15;
        *(uint4*)&Wt[nrow][chunk * 8] = *(const uint4*)(Wtg + nrow * K + chunk * 8);
    }
    __syncthreads();
    int lane = t & 63, wid = t >> 6;
    int col = lane & 15, quad = lane >> 4;
    int nstrips = M / 16;
    int stride = gridDim.x * 4;
    int s = blockIdx.x * 4 + wid;
    if (s >= nstrips) return;

    auto loadA = [&](int strip, short8 af[4]) {
        int row0 = strip * 16;
        if (CVT) {
            const float* Af = (const float*)Av + (size_t)(row0 + col) * K + quad * 8;
            #pragma unroll
            for (int ks = 0; ks < 4; ks++) {
                float4 f0 = *(const float4*)(Af + ks * 32);
                float4 f1 = *(const float4*)(Af + ks * 32 + 4);
                short8 v;
                v[0] = (short)f2bf(f0.x); v[1] = (short)f2bf(f0.y); v[2] = (short)f2bf(f0.z); v[3] = (short)f2bf(f0.w);
                v[4] = (short)f2bf(f1.x); v[5] = (short)f2bf(f1.y); v[6] = (short)f2bf(f1.z); v[7] = (short)f2bf(f1.w);
                af[ks] = v;
            }
        } else {
            const unsigned short* Ab = (const unsigned short*)Av + (size_t)(row0 + col) * K + quad * 8;
            #pragma unroll
            for (int ks = 0; ks < 4; ks++) af[ks] = *(const short8*)(Ab + ks * 32);
        }
    };

    short8 cur[4];
    loadA(s, cur);
    while (true) {
        int snext = s + stride;
        bool has = (snext < nstrips);
        short8 nxt[4];
        if (has) loadA(snext, nxt);

        floatx4 acc[NT];
        #pragma unroll
        for (int i = 0; i < NT; i++) acc[i] = (floatx4){0.f, 0.f, 0.f, 0.f};
        #pragma unroll
        for (int ks = 0; ks < 4; ks++) {
            #pragma unroll
            for (int nt = 0; nt < NT; nt++) {
                short8 bfrag = *(const short8*)&Wt[nt * 16 + col][ks * 32 + quad * 8];
                acc[nt] = __builtin_amdgcn_mfma_f32_16x16x32_bf16(cur[ks], bfrag, acc[nt], 0, 0, 0);
            }
        }
        int row0 = s * 16;
        #pragma unroll
        for (int r = 0; r < 4; r++) {
            float dv = dinv[row0 + quad * 4 + r];
            #pragma unroll
            for (int nt = 0; nt < NT; nt++)
                Ost[wid][quad * 4 + r][nt * 16 + col] = f2bf(acc[nt][r] * dv);
        }
        #pragma unroll
        for (int i = 0; i < NU; i++) {
            int idx = i * 64 + lane;
            int rr = (NC == 128) ? (idx >> 4) : (idx >> 3);
            int cc = (NC == 128) ? (idx & 15) : (idx & 7);
            ((uint4*)&Y[(size_t)(row0 + rr) * NC])[cc] = *(uint4*)&Ost[wid][rr][cc * 8];
        }
        if (!has) break;
        s = snext;
        #pragma unroll
        for (int ks = 0; ks < 4; ks++) cur[ks] = nxt[ks];
    }
}

// ---------------- gather + epilogue (bf16 rows), x4 unroll ----------------

__device__ __forceinline__ void acc8(float* a, uint4 v) {
    a[0] += bflo(v.x); a[1] += bfhi(v.x);
    a[2] += bflo(v.y); a[3] += bfhi(v.y);
    a[4] += bflo(v.z); a[5] += bfhi(v.z);
    a[6] += bflo(v.w); a[7] += bfhi(v.w);
}

// 128 ch bf16: 16 threads/node, 8 ch (one uint4) per thread, 16 nodes/block
__global__ __launch_bounds__(256) void k_gather_relu_bf(const uint4* __restrict__ y, const int* __restrict__ csr,
                                                        const int* __restrict__ row_ptr, const float* __restrict__ dinv,
                                                        const float* __restrict__ bias, uint4* __restrict__ h, int n) {
    int node = blockIdx.x * 16 + (threadIdx.x >> 4);
    int c = threadIdx.x & 15;
    if (node >= n) return;
    int s0 = row_ptr[node], s1 = row_ptr[node + 1];
    float a[8] = {};
    acc8(a, y[(size_t)node * 16 + c]);       // self loop
    int p = s0;
    for (; p + 4 <= s1; p += 4) {
        int i0 = csr[p], i1 = csr[p + 1], i2 = csr[p + 2], i3 = csr[p + 3];
        uint4 v0 = y[(size_t)i0 * 16 + c];
        uint4 v1 = y[(size_t)i1 * 16 + c];
        uint4 v2 = y[(size_t)i2 * 16 + c];
        uint4 v3 = y[(size_t)i3 * 16 + c];
        acc8(a, v0); acc8(a, v1); acc8(a, v2); acc8(a, v3);
    }
    for (; p < s1; p++) acc8(a, y[(size_t)csr[p] * 16 + c]);
    float s = dinv[node];
    float4 b0 = ((const float4*)bias)[c * 2];
    float4 b1 = ((const float4*)bias)[c * 2 + 1];
    float r0 = fmaxf(s * a[0] + b0.x, 0.f), r1 = fmaxf(s * a[1] + b0.y, 0.f);
    float r2 = fmaxf(s * a[2] + b0.z, 0.f), r3 = fmaxf(s * a[3] + b0.w, 0.f);
    float r4 = fmaxf(s * a[4] + b1.x, 0.f), r5 = fmaxf(s * a[5] + b1.y, 0.f);
    float r6 = fmaxf(s * a[6] + b1.z, 0.f), r7 = fmaxf(s * a[7] + b1.w, 0.f);
    uint4 o;
    o.x = ((unsigned)f2bf(r1) << 16) | f2bf(r0);
    o.y = ((unsigned)f2bf(r3) << 16) | f2bf(r2);
    o.z = ((unsigned)f2bf(r5) << 16) | f2bf(r4);
    o.w = ((unsigned)f2bf(r7) << 16) | f2bf(r6);
    h[(size_t)node * 16 + c] = o;
}

// 64 ch bf16 + log-softmax: 8 threads/node, 8 ch per thread, 32 nodes/block. fp32 output.
__global__ __launch_bounds__(256) void k_gather_lsm_bf(const uint4* __restrict__ y, const int* __restrict__ csr,
                                                       const int* __restrict__ row_ptr, const float* __restrict__ dinv,
                                                       const float* __restrict__ bias, float4* __restrict__ out4, int n) {
    int node = blockIdx.x * 32 + (threadIdx.x >> 3);
    int c = threadIdx.x & 7;
    if (node >= n) return;
    int s0 = row_ptr[node], s1 = row_ptr[node + 1];
    float a[8] = {};
    acc8(a, y[(size_t)node * 8 + c]);
    int p = s0;
    for (; p + 4 <= s1; p += 4) {
        int i0 = csr[p], i1 = csr[p + 1], i2 = csr[p + 2], i3 = csr[p + 3];
        uint4 v0 = y[(size_t)i0 * 8 + c];
        uint4 v1 = y[(size_t)i1 * 8 + c];
        uint4 v2 = y[(size_t)i2 * 8 + c];
        uint4 v3 = y[(size_t)i3 * 8 + c];
        acc8(a, v0); acc8(a, v1); acc8(a, v2); acc8(a, v3);
    }
    for (; p < s1; p++) acc8(a, y[(size_t)csr[p] * 8 + c]);
    float s = dinv[node];
    float4 b0 = ((const float4*)bias)[c * 2];
    float4 b1 = ((const float4*)bias)[c * 2 + 1];
    float v[8];
    v[0] = s * a[0] + b0.x; v[1] = s * a[1] + b0.y; v[2] = s * a[2] + b0.z; v[3] = s * a[3] + b0.w;
    v[4] = s * a[4] + b1.x; v[5] = s * a[5] + b1.y; v[6] = s * a[6] + b1.z; v[7] = s * a[7] + b1.w;
    float m = v[0];
    #pragma unroll
    for (int i = 1; i < 8; i++) m = fmaxf(m, v[i]);
    #pragma unroll
    for (int o = 4; o > 0; o >>= 1) m = fmaxf(m, __shfl_xor(m, o));
    float sum = 0.f;
    #pragma unroll
    for (int i = 0; i < 8; i++) sum += expf(v[i] - m);
    #pragma unroll
    for (int o = 4; o > 0; o >>= 1) sum += __shfl_xor(sum, o);
    float lse = m + logf(sum);
    out4[(size_t)node * 16 + c * 2]     = make_float4(v[0] - lse, v[1] - lse, v[2] - lse, v[3] - lse);
    out4[(size_t)node * 16 + c * 2 + 1] = make_float4(v[4] - lse, v[5] - lse, v[6] - lse, v[7] - lse);
}

// ---------------- launch ----------------

extern "C" void kernel_launch(void* const* d_in, const int* in_sizes, int n_in,
                              void* d_out, int out_size, void* d_ws, size_t ws_size,
                              hipStream_t stream) {
    const float* x  = (const float*)d_in[0];
    const int*   ei = (const int*)d_in[1];
    const float* W1 = (const float*)d_in[2];
    const float* b1 = (const float*)d_in[3];
    const float* W2 = (const float*)d_in[4];
    const float* b2 = (const float*)d_in[5];
    const float* W3 = (const float*)d_in[6];
    const float* b3 = (const float*)d_in[7];
    float* out = (float*)d_out;

    const int N = NN, E = NE;

    char* ws = (char*)d_ws;
    size_t off = 0;
    auto alloc = [&](size_t bytes) -> void* {
        void* p = ws + off;
        off += bytes;
        off = (off + 255) & ~(size_t)255;
        return p;
    };
    int*            row_ptr = (int*)alloc((size_t)(N + 1) * 4);
    float*          dinvv   = (float*)alloc((size_t)N * 4);
    int*            bcur    = (int*)alloc(512 * 4);
    int*            bbase   = (int*)alloc(512 * 4);
    int*            bbuf    = (int*)alloc((size_t)NBUK * BCAP * 4);
    int*            csr     = (int*)alloc((size_t)E * 4);
    unsigned short* wt1     = (unsigned short*)alloc(128 * 128 * 2);
    unsigned short* wt2     = (unsigned short*)alloc(128 * 128 * 2);
    unsigned short* wt3     = (unsigned short*)alloc(64 * 128 * 2);
    unsigned short* yb      = (unsigned short*)alloc((size_t)N * 128 * 2);
    unsigned short* hb      = (unsigned short*)alloc((size_t)N * 128 * 2);
    (void)ws_size; (void)in_sizes; (void)n_in; (void)out_size;

    const int* srcp = ei;
    const int* dstp = ei + E;

    hipMemsetAsync(bcur, 0, 512 * 4, stream);
    k_wprep_all<<<160, 256, 0, stream>>>(W1, W2, W3, wt1, wt2, wt3);
    k_bucket<<<(E + 4095) / 4096, 256, 0, stream>>>((const int4*)srcp, (const int4*)dstp, bcur, bbuf, E);
    k_scanbuckets<<<1, 64, 0, stream>>>(bcur, bbase, NBUK, row_ptr, N, E);
    k_build<<<NBUK, 256, 0, stream>>>(bcur, bbase, bbuf, row_ptr, csr, dinvv, N);

    // Layer 1 (fp32 x converted in-register)
    k_mfma<128, true><<<768, 256, 0, stream>>>(x, wt1, dinvv, yb, N);
    k_gather_relu_bf<<<N / 16, 256, 0, stream>>>((const uint4*)yb, csr, row_ptr, dinvv, b1, (uint4*)hb, N);
    // Layer 2
    k_mfma<128, false><<<768, 256, 0, stream>>>(hb, wt2, dinvv, yb, N);
    k_gather_relu_bf<<<N / 16, 256, 0, stream>>>((const uint4*)yb, csr, row_ptr, dinvv, b2, (uint4*)hb, N);
    // Layer 3 (128 -> 64) + log-softmax
    k_mfma<64, false><<<768, 256, 0, stream>>>(hb, wt3, dinvv, yb, N);
    k_gather_lsm_bf<<<N / 32, 256, 0, stream>>>((const uint4*)yb, csr, row_ptr, dinvv, b3, (float4*)out, N);
}